// Round 2
// baseline (1498.097 us; speedup 1.0000x reference)
//
#include <hip/hip_runtime.h>
#include <hip/hip_bf16.h>
#include <cstdint>

// GMMSA: proj(1x1) -> GroupNorm(2) -> 3x windowed self-attn (q==k) -> fuse(1x1)
// Identity used: attn_g rows == attn rows at gidx  =>  global-token branch is a
// no-op; outputs are exactly (fuse(concat(sw_i * attn_i @ v_i)), attn_0..2).
// I/O dtype: float32 (per reference). Internal xp/yf staged as bf16 in d_ws.

typedef __hip_bfloat16 bf16;
typedef __hip_bfloat162 bf162;

#define IMG 192
#define PIX (IMG*IMG)   // 36864
#define CIN 180
#define CMID 360

__device__ __forceinline__ float b2f(bf16 v){ return __bfloat162float(v); }
__device__ __forceinline__ bf16 f2b(float v){ return __float2bfloat16(v); }

__device__ __forceinline__ void ld2(const float* p, float& a, float& b){
    float2 v = *reinterpret_cast<const float2*>(p); a = v.x; b = v.y;
}
__device__ __forceinline__ void ld2(const bf16* p, float& a, float& b){
    bf162 v = *reinterpret_cast<const bf162*>(p); a = b2f(v.x); b = b2f(v.y);
}
__device__ __forceinline__ void st2(float* p, float a, float b){
    *reinterpret_cast<float2*>(p) = make_float2(a, b);
}
__device__ __forceinline__ void st2(bf16* p, float a, float b){
    bf162 w; w.x = f2b(a); w.y = f2b(b);
    *reinterpret_cast<bf162*>(p) = w;
}

// ---- 1x1-conv GEMM: Y[b,o,p] = sum_c W[o,c] X[b,c,p] + B[o]  (+GN stats) ----
template<int OT, bool STATS, typename XT, typename YT>
__global__ __launch_bounds__(256) void k_gemm(
    const float* __restrict__ W, const float* __restrict__ Bv,
    const XT* __restrict__ X, YT* __restrict__ Y,
    float* __restrict__ stats, int M, int K)
{
    __shared__ float red[4][4];
    const int tid = threadIdx.x;
    const int o0 = blockIdx.x * OT;
    const int bz = blockIdx.z;
    const int p  = blockIdx.y * 512 + tid*2;

    float acc0[OT], acc1[OT];
#pragma unroll
    for (int j=0;j<OT;j++){acc0[j]=0.f;acc1[j]=0.f;}
    const XT* Xp = X + (size_t)bz*K*PIX + p;
    const float* Wp = W + (size_t)o0*K;
    for (int c = 0; c < K; ++c) {
        float x0, x1;
        ld2(Xp + (size_t)c*PIX, x0, x1);
#pragma unroll
        for (int j=0;j<OT;j++){
            float wv = Wp[j*K + c];            // uniform addr -> SGPR broadcast
            acc0[j] = fmaf(x0, wv, acc0[j]);
            acc1[j] = fmaf(x1, wv, acc1[j]);
        }
    }
    float s0=0.f,s1=0.f,q0=0.f,q1=0.f;
#pragma unroll
    for (int j=0;j<OT;j++){
        int o = o0 + j;
        float bb = Bv[o];
        float v0 = acc0[j] + bb, v1 = acc1[j] + bb;
        st2(Y + (size_t)(bz*M + o)*PIX + p, v0, v1);
        if (STATS) {
            if (o < 180){ s0 += v0+v1; q0 += fmaf(v0,v0,v1*v1); }
            else        { s1 += v0+v1; q1 += fmaf(v0,v0,v1*v1); }
        }
    }
    if (STATS) {
#pragma unroll
        for (int off=32; off>0; off>>=1){
            s0 += __shfl_down(s0, off); s1 += __shfl_down(s1, off);
            q0 += __shfl_down(q0, off); q1 += __shfl_down(q1, off);
        }
        int wv = tid>>6, ln = tid&63;
        if (ln==0){ red[0][wv]=s0; red[1][wv]=s1; red[2][wv]=q0; red[3][wv]=q1; }
        __syncthreads();
        if (tid==0){
            float r0=red[0][0]+red[0][1]+red[0][2]+red[0][3];
            float r1=red[1][0]+red[1][1]+red[1][2]+red[1][3];
            float r2=red[2][0]+red[2][1]+red[2][2]+red[2][3];
            float r3=red[3][0]+red[3][1]+red[3][2]+red[3][3];
            atomicAdd(&stats[(bz*2+0)*2+0], r0);
            atomicAdd(&stats[(bz*2+1)*2+0], r1);
            atomicAdd(&stats[(bz*2+0)*2+1], r2);
            atomicAdd(&stats[(bz*2+1)*2+1], r3);
        }
    }
}

// ---- finalize GN stats: stats[0..7]=sum/sumsq per (b,g); writes mu/rsig at [8..15] ----
__global__ void k_stats(float* stats)
{
    int i = threadIdx.x;
    if (i < 4) {
        const float n = 180.0f*36864.0f;
        float mu  = stats[i*2] / n;
        float var = stats[i*2+1]/n - mu*mu;
        stats[8 + i*2]     = mu;
        stats[8 + i*2 + 1] = rsqrtf(var + 1e-5f);
    }
}

// ---- windowed self-attention (q==k), one (window, head, row-split) per block ----
// Sm stored transposed [s][t_local] with stride TR+1 (odd) -> conflict-free phases.
template<int WS, int HE, int CHN, int SI, int SPLIT, int RROW, int NSC>
__global__ __launch_bounds__(256) void k_attn(
    const bf16* __restrict__ xp, const float* __restrict__ musig,
    const float* __restrict__ gamma, const float* __restrict__ beta,
    const float* __restrict__ swt,
    float* __restrict__ atn, bf16* __restrict__ yf)
{
    constexpr int T = WS*WS;
    constexpr int NWIN = IMG/WS;
    constexpr int TR = T/SPLIT;       // rows of S this block owns
    constexpr int PP = TR/RROW;
    constexpr int SLEN = T/NSC;
    constexpr int ST = TR + 1;        // odd stride
    __shared__ float qs[T*CHN];
    __shared__ float vs[T*CHN];
    __shared__ float Sm[T*ST];        // [s][tl]
    __shared__ float rinv[TR];

    const int tid = threadIdx.x;
    const int wid = blockIdx.x;
    const int head = blockIdx.y;
    const int tb = blockIdx.z * TR;
    const int bi = wid / (NWIN*NWIN);
    const int r2 = wid - bi*(NWIN*NWIN);
    const int wy = r2 / NWIN;
    const int wx = r2 - wy*NWIN;

    // load Q/V with GroupNorm applied; rolls folded into source-pixel math
    for (int idx = tid; idx < 2*T*CHN; idx += 256) {
        int qv = idx / (T*CHN);
        int rem = idx - qv*(T*CHN);
        int t = rem / CHN;
        int c = rem - t*CHN;
        int chan = SI*120 + qv*60 + c*HE + head;
        int r = t / WS, cc = t - r*WS;
        int sh = wy*WS + r - WS/2;  if (sh < 0) sh += IMG;
        int sw = wx*WS + cc + WS/2; if (sw >= IMG) sw -= IMG;
        float val = b2f(xp[((size_t)(bi*CMID + chan)*IMG + sh)*IMG + sw]);
        int g = (chan >= 180) ? 1 : 0;
        float mu = musig[(bi*2+g)*2+0];
        float rs = musig[(bi*2+g)*2+1];
        float xn = fmaf((val - mu)*rs, gamma[chan], beta[chan]);
        if (qv) vs[t*CHN+c] = xn; else qs[t*CHN+c] = xn;
    }
    __syncthreads();

    // S[t,s] = (q[t].q[s]) / HE  for t in [tb, tb+TR); q[s] reads are wave-uniform
    constexpr float invHE = 1.0f/(float)HE;
    for (int item = tid; item < PP*NSC; item += 256) {
        int sc = item / PP;
        int p2 = item - sc*PP;
        int tl0 = p2*RROW;
        float qreg[RROW][CHN];
#pragma unroll
        for (int rr=0; rr<RROW; ++rr)
#pragma unroll
            for (int c=0;c<CHN;c++)
                qreg[rr][c] = qs[(tb + tl0 + rr)*CHN + c];
        for (int j=0;j<SLEN;++j) {
            int s = sc*SLEN + j;
            float d[RROW];
#pragma unroll
            for (int rr=0;rr<RROW;++rr) d[rr]=0.f;
#pragma unroll
            for (int c=0;c<CHN;c++){
                float qc = qs[s*CHN + c];
#pragma unroll
                for (int rr=0;rr<RROW;++rr)
                    d[rr] = fmaf(qreg[rr][c], qc, d[rr]);
            }
#pragma unroll
            for (int rr=0;rr<RROW;++rr)
                Sm[s*ST + tl0 + rr] = d[rr]*invHE;
        }
    }
    __syncthreads();

    // per-row softmax (exp stored in place, 1/sum in rinv)
    for (int tl = tid; tl < TR; tl += 256) {
        float mx = -1e30f;
        for (int s=0;s<T;s++) mx = fmaxf(mx, Sm[s*ST + tl]);
        float sum = 0.f;
        for (int s=0;s<T;s++){
            float e = __expf(Sm[s*ST + tl] - mx);
            Sm[s*ST + tl] = e;
            sum += e;
        }
        rinv[tl] = 1.0f/sum;
    }
    __syncthreads();

    // write P (== out_attn, global branch is identity) — coalesced float2
    {
        size_t abase = ((size_t)wid*HE + head)*(size_t)(T*T) + (size_t)tb*T;
        for (int e2 = tid; e2 < TR*T/2; e2 += 256) {
            int e = e2*2;
            int tl = e / T;
            int s = e - tl*T;
            float ri = rinv[tl];
            st2(atn + abase + e, Sm[s*ST + tl]*ri, Sm[(s+1)*ST + tl]*ri);
        }
    }

    // out[t,c] = (sum_s e[t,s] v[s,c]) * rinv[t] * scale_w -> scatter to y_fused
    float swf = swt[SI];
    for (int item = tid; item < (TR/2)*CHN; item += 256) {
        int tp = item / CHN;
        int c = item - tp*CHN;
        int tl0 = tp*2;
        float a0=0.f, a1=0.f;
        for (int s=0;s<T;s++){
            float vv = vs[s*CHN + c];
            a0 = fmaf(Sm[s*ST + tl0],   vv, a0);
            a1 = fmaf(Sm[s*ST + tl0+1], vv, a1);
        }
        int yc = SI*60 + c*HE + head;
#pragma unroll
        for (int k2=0;k2<2;k2++){
            int tl = tl0 + k2;
            int t = tb + tl;
            float ov = (k2 ? a1 : a0) * rinv[tl] * swf;
            int r = t / WS, cc = t - r*WS;
            int sh = wy*WS + r - WS/2;  if (sh < 0) sh += IMG;
            int sw = wx*WS + cc + WS/2; if (sw >= IMG) sw -= IMG;
            yf[((size_t)(bi*CIN + yc)*IMG + sh)*IMG + sw] = f2b(ov);
        }
    }
}

extern "C" void kernel_launch(void* const* d_in, const int* in_sizes, int n_in,
                              void* d_out, int out_size, void* d_ws, size_t ws_size,
                              hipStream_t stream)
{
    (void)in_sizes; (void)n_in; (void)out_size; (void)ws_size;
    const float* x   = (const float*)d_in[0];
    const float* pw  = (const float*)d_in[1];
    const float* pb  = (const float*)d_in[2];
    const float* gg  = (const float*)d_in[3];
    const float* gb  = (const float*)d_in[4];
    // d_in[5] token_scores: unused (global-token branch is mathematically identity)
    const float* swt = (const float*)d_in[6];
    const float* fw  = (const float*)d_in[7];
    const float* fb  = (const float*)d_in[8];

    float* out  = (float*)d_out;
    float* atn0 = out + 13271040;            // (4608,2,16,16)
    float* atn1 = out + 15630336;            // (1152,4,64,64)
    float* atn2 = out + 34504704;            // (512,6,144,144)

    char* ws = (char*)d_ws;
    bf16*  xp    = (bf16*)ws;                               // 26,542,080 elems
    bf16*  yf    = (bf16*)(ws + 53084160);                  // 13,271,040 elems
    float* stats = (float*)(ws + 53084160 + 26542080);      // 16 floats

    hipMemsetAsync(stats, 0, 64, stream);
    // proj GEMM + GN partial sums
    k_gemm<8,true,float,bf16><<<dim3(45,72,2), 256, 0, stream>>>(pw, pb, x, xp, stats, 360, 180);
    k_stats<<<1, 64, 0, stream>>>(stats);
    // attention scales: <WS,HE,CHN,SI,SPLIT,RROW,NSC>
    k_attn<4, 2, 30, 0, 1, 1, 16><<<dim3(4608,2,1), 256, 0, stream>>>(xp, stats+8, gg, gb, swt, atn0, yf);
    k_attn<8, 4, 15, 1, 1, 2, 8 ><<<dim3(1152,4,1), 256, 0, stream>>>(xp, stats+8, gg, gb, swt, atn1, yf);
    k_attn<12,6, 10, 2, 2, 2, 8 ><<<dim3(512, 6,2), 256, 0, stream>>>(xp, stats+8, gg, gb, swt, atn2, yf);
    // fuse GEMM (scale_weights already folded into yf)
    k_gemm<6,false,bf16,float><<<dim3(30,72,2), 256, 0, stream>>>(fw, fb, yf, out, nullptr, 180, 180);
}